// Round 8
// baseline (548.454 us; speedup 1.0000x reference)
//
#include <hip/hip_runtime.h>

typedef __bf16 bf16_t;
typedef bf16_t bf16x8 __attribute__((ext_vector_type(8)));
typedef float f32x4 __attribute__((ext_vector_type(4)));
typedef unsigned short u16;
typedef unsigned long long u64;

__device__ __forceinline__ u16 f2bf(float f) {
  union { float f; unsigned u; } v; v.f = f;
  unsigned r = v.u + 0x7FFFu + ((v.u >> 16) & 1u);
  return (u16)(r >> 16);
}
__device__ __forceinline__ bf16x8 ld8(const u16* p) {
  return *reinterpret_cast<const bf16x8*>(p);
}
__device__ __forceinline__ void gload_lds16(const void* g, void* l) {
  __builtin_amdgcn_global_load_lds(
      (const __attribute__((address_space(1))) void*)g,
      (__attribute__((address_space(3))) void*)l, 16, 0, 0);
}

struct Ptrs4 { const float* p[4]; };

// ---------------- f32 -> bf16 conversions ----------------
struct CvtJob { const float* s; u16* d; int n; };
struct CvtJobs { CvtJob j[8]; };

__global__ __launch_bounds__(256) void cvt_multi(CvtJobs jobs) {
  CvtJob J = jobs.j[blockIdx.y];
  for (int i = blockIdx.x * 256 + threadIdx.x; i < J.n; i += gridDim.x * 256)
    J.d[i] = f2bf(J.s[i]);
}

// in: [z][C][N] f32 -> out: [z][N][C] bf16
__global__ __launch_bounds__(256) void transpose_cvt(
    const float* __restrict__ in, u16* __restrict__ out, int C, int N) {
  __shared__ float t[32][33];
  int tx = threadIdx.x & 31, ty = threadIdx.x >> 5;
  int n0 = blockIdx.x * 32, c0 = blockIdx.y * 32;
  long zi = (long)blockIdx.z * C * N, zo = (long)blockIdx.z * N * C;
#pragma unroll
  for (int i = 0; i < 4; ++i)
    t[ty + 8 * i][tx] = in[zi + (long)(c0 + ty + 8 * i) * N + n0 + tx];
  __syncthreads();
#pragma unroll
  for (int i = 0; i < 4; ++i)
    out[zo + (long)(n0 + ty + 8 * i) * C + c0 + tx] = f2bf(t[tx][ty + 8 * i]);
}

// ---------------- GEMM: C[m][n] = sum_k A[m][k]*X[z][n][k] (+bias[m]) ----------------
// MODE 0: out1 bf16 [z][N][M] (transposed store)
// MODE 1: out1 bf16 [z][M][N]
// MODE 2: out1 f32  [z][M][N], bias + optional residual
// MODE 3: KV: rows<256 -> out1 = K, swizzled 16KB key-tiles [z][N/32][32][256]
//             rows>=256 -> out2 = V, swizzled 16KB key-tiles [z][N/32][256][32]
//         swizzle: byte_in_tile ^= ((row&7)<<4), row=key for K, row=d for V
template <int MODE>
__global__ __launch_bounds__(256) void gemm_k(
    const u16* __restrict__ A, const u16* __restrict__ X,
    const float* __restrict__ bias, const float* __restrict__ bias2,
    void* __restrict__ out1, void* __restrict__ out2,
    const float* __restrict__ res, int M, int N, int K) {
  __shared__ __attribute__((aligned(16))) u16 As[64][40];
  __shared__ __attribute__((aligned(16))) u16 Bs[64][40];
  const int tid = threadIdx.x;
  const int m0 = blockIdx.y * 64, n0 = blockIdx.x * 64, z = blockIdx.z;
  const long Xz = (long)z * N * K;
  const int arow = tid >> 2, acol = (tid & 3) * 8;
  const int w = tid >> 6, lane = tid & 63, g = lane >> 4, ln = lane & 15;
  const int wm = (w >> 1) * 32, wn = (w & 1) * 32;
  f32x4 zero = {0.f, 0.f, 0.f, 0.f};
  f32x4 acc[2][2];
#pragma unroll
  for (int i = 0; i < 2; ++i)
#pragma unroll
    for (int j = 0; j < 2; ++j) acc[i][j] = zero;

  for (int k0 = 0; k0 < K; k0 += 32) {
    int4 av = *reinterpret_cast<const int4*>(A + (long)(m0 + arow) * K + k0 + acol);
    int4 bv = *reinterpret_cast<const int4*>(X + Xz + (long)(n0 + arow) * K + k0 + acol);
    __syncthreads();
    *reinterpret_cast<int4*>(&As[arow][acol]) = av;
    *reinterpret_cast<int4*>(&Bs[arow][acol]) = bv;
    __syncthreads();
    bf16x8 a0 = ld8(&As[wm + ln][g * 8]);
    bf16x8 a1 = ld8(&As[wm + 16 + ln][g * 8]);
    bf16x8 b0 = ld8(&Bs[wn + ln][g * 8]);
    bf16x8 b1 = ld8(&Bs[wn + 16 + ln][g * 8]);
    acc[0][0] = __builtin_amdgcn_mfma_f32_16x16x32_bf16(a0, b0, acc[0][0], 0, 0, 0);
    acc[0][1] = __builtin_amdgcn_mfma_f32_16x16x32_bf16(a0, b1, acc[0][1], 0, 0, 0);
    acc[1][0] = __builtin_amdgcn_mfma_f32_16x16x32_bf16(a1, b0, acc[1][0], 0, 0, 0);
    acc[1][1] = __builtin_amdgcn_mfma_f32_16x16x32_bf16(a1, b1, acc[1][1], 0, 0, 0);
  }

#pragma unroll
  for (int i = 0; i < 2; ++i) {
#pragma unroll
    for (int j = 0; j < 2; ++j) {
      int mr0 = m0 + wm + 16 * i + g * 4;
      int nc = n0 + wn + 16 * j + ln;
      if (MODE == 0) {
        u64 pk = 0;
#pragma unroll
        for (int r = 0; r < 4; ++r) {
          float val = acc[i][j][r] + (bias ? bias[mr0 + r] : 0.f);
          pk |= (u64)f2bf(val) << (16 * r);
        }
        *reinterpret_cast<u64*>((u16*)out1 + ((long)z * N + nc) * M + mr0) = pk;
      } else if (MODE == 1) {
#pragma unroll
        for (int r = 0; r < 4; ++r) {
          float val = acc[i][j][r] + (bias ? bias[mr0 + r] : 0.f);
          ((u16*)out1)[((long)z * M + mr0 + r) * N + nc] = f2bf(val);
        }
      } else if (MODE == 2) {
#pragma unroll
        for (int r = 0; r < 4; ++r) {
          long idx = ((long)z * M + mr0 + r) * N + nc;
          float val = acc[i][j][r] + bias[mr0 + r];
          if (res) val += res[idx];
          ((float*)out1)[idx] = val;
        }
      } else {
        long tbase = ((long)z * N * 256 + (long)(nc >> 5) * 8192) * 2;  // tile byte base
        if (mr0 < 256) {
          // K tile: [key 32][ch 256] bf16, byte ^= ((key&7)<<4)
          u64 pk = 0;
#pragma unroll
          for (int r = 0; r < 4; ++r)
            pk |= (u64)f2bf(acc[i][j][r] + bias[mr0 + r]) << (16 * r);
          int byteoff = ((nc & 31) * 512 + mr0 * 2) ^ ((nc & 7) << 4);
          *reinterpret_cast<u64*>((char*)out1 + tbase + byteoff) = pk;
        } else {
          // V tile: [d 256][key 32] bf16, byte ^= ((d&7)<<4)
#pragma unroll
          for (int r = 0; r < 4; ++r) {
            int d = mr0 - 256 + r;
            int byteoff = (d * 64 + (nc & 31) * 2) ^ ((d & 7) << 4);
            *reinterpret_cast<u16*>((char*)out2 + tbase + byteoff) =
                f2bf(acc[i][j][r] + bias2[d]);
          }
        }
      }
    }
  }
}

// ---------------- flash attention: 4-wave block, shared-LDS K/V, split-K x2 ----
// QT: [z][N][256] bf16 ; Kt,Vt: swizzled 16KB key-tiles [z][N/32][8192 u16]
// O: [z][N][256] bf16.  Block 256 thr = 4 waves: wave w -> qg=w&1 (32 queries),
// kseg=w>>1 (half the keys). Swapped QK^T (lane owns a query column).
__global__ __launch_bounds__(256, 1) void attn_k(
    const u16* __restrict__ QT, const u16* __restrict__ Kt,
    const u16* __restrict__ Vt, u16* __restrict__ O, int N) {
  __shared__ __attribute__((aligned(16))) char stage[2][2][2][16384];
  __shared__ __attribute__((aligned(16))) u16 Ps[4][32][40];
  __shared__ float mls[2][2][2][16];
  const int tid = threadIdx.x;
  const int w = tid >> 6, lane = tid & 63;
  const int g = lane >> 4, ln = lane & 15;
  const int qg = w & 1, kseg = w >> 1;
  // XCD-aware swizzle: pin each z to 2 XCDs so its 4MB K+V stays L2-resident
  int gx = gridDim.x, bx = blockIdx.x, z = blockIdx.y;
  if (!(gx & 1)) {
    int f = bx + z * gx;
    int xcd = f & 7, j = f >> 3;
    z = xcd >> 1;
    bx = (xcd & 1) * (gx >> 1) + j;
  }
  const int qbase = bx * 64 + qg * 32;
  const float scale = 0.0625f;  // 1/sqrt(256)
  const int nt = N >> 6;        // 32-key tiles per kseg
  const long ztile = (long)z * (N >> 5);

  // Q as B-fragments: qf[qh][cc], col=query=ln within half qh
  bf16x8 qf[2][8];
#pragma unroll
  for (int qh = 0; qh < 2; ++qh) {
    const u16* qp = QT + ((long)z * N + qbase + qh * 16 + ln) * 256 + g * 8;
#pragma unroll
    for (int cc = 0; cc < 8; ++cc) qf[qh][cc] = ld8(qp + cc * 32);
  }
  f32x4 zero = {0.f, 0.f, 0.f, 0.f};
  f32x4 oacc[16][2];
#pragma unroll
  for (int ct = 0; ct < 16; ++ct) {
    oacc[ct][0] = zero;
    oacc[ct][1] = zero;
  }
  float mrow[2] = {-1e30f, -1e30f}, lrow[2] = {0.f, 0.f};

  // wave w stages its kseg's K (w even) or V (w odd) tile: 16 x 1KB chunks
  const u16* gKV = (w & 1) ? Vt : Kt;
  const long tb = ztile + (long)kseg * nt;
  auto stage_tile = [&](int buf, int t) {
    const char* gp = (const char*)(gKV + (tb + t) * 8192) + lane * 16;
    char* lp = &stage[buf][kseg][w & 1][0];
#pragma unroll
    for (int q = 0; q < 16; ++q) gload_lds16(gp + q * 1024, lp + q * 1024);
  };

  stage_tile(0, 0);
  asm volatile("s_waitcnt vmcnt(0)" ::: "memory");
  __syncthreads();

  const int swz = (ln & 7) << 4;
  for (int t = 0; t < nt; ++t) {
    const int buf = t & 1;
    if (t + 1 < nt) stage_tile(buf ^ 1, t + 1);
    const char* Kb = &stage[buf][kseg][0][0];
    const char* Vb = &stage[buf][kseg][1][0];
    // S^T = K . Q^T : s[kh][qh], lane col = query ln, rows = keys
    f32x4 s[2][2];
    s[0][0] = zero; s[0][1] = zero; s[1][0] = zero; s[1][1] = zero;
#pragma unroll
    for (int cc = 0; cc < 8; ++cc) {
      bf16x8 k0 = *reinterpret_cast<const bf16x8*>(Kb + ((ln * 512 + cc * 64 + g * 16) ^ swz));
      bf16x8 k1 = *reinterpret_cast<const bf16x8*>(Kb + (((16 + ln) * 512 + cc * 64 + g * 16) ^ swz));
      s[0][0] = __builtin_amdgcn_mfma_f32_16x16x32_bf16(k0, qf[0][cc], s[0][0], 0, 0, 0);
      s[0][1] = __builtin_amdgcn_mfma_f32_16x16x32_bf16(k0, qf[1][cc], s[0][1], 0, 0, 0);
      s[1][0] = __builtin_amdgcn_mfma_f32_16x16x32_bf16(k1, qf[0][cc], s[1][0], 0, 0, 0);
      s[1][1] = __builtin_amdgcn_mfma_f32_16x16x32_bf16(k1, qf[1][cc], s[1][1], 0, 0, 0);
    }
#pragma unroll
    for (int qh = 0; qh < 2; ++qh) {
      float x[8];
#pragma unroll
      for (int r = 0; r < 4; ++r) { x[r] = s[0][qh][r] * scale; x[4 + r] = s[1][qh][r] * scale; }
      float lm = fmaxf(fmaxf(fmaxf(x[0], x[1]), fmaxf(x[2], x[3])),
                       fmaxf(fmaxf(x[4], x[5]), fmaxf(x[6], x[7])));
      lm = fmaxf(lm, __shfl_xor(lm, 16));
      lm = fmaxf(lm, __shfl_xor(lm, 32));
      // T13 defer-max
      if (!__all(lm - mrow[qh] <= 8.0f)) {
        float nm = fmaxf(mrow[qh], lm);
        float fac = __expf(mrow[qh] - nm);
        mrow[qh] = nm;
        lrow[qh] *= fac;
#pragma unroll
        for (int ct = 0; ct < 16; ++ct)
#pragma unroll
          for (int r = 0; r < 4; ++r) oacc[ct][qh][r] *= fac;
      }
      float ps = 0.f;
#pragma unroll
      for (int j2 = 0; j2 < 8; ++j2) { x[j2] = __expf(x[j2] - mrow[qh]); ps += x[j2]; }
      ps += __shfl_xor(ps, 16);
      ps += __shfl_xor(ps, 32);
      lrow[qh] += ps;
      u64 plo = (u64)f2bf(x[0]) | ((u64)f2bf(x[1]) << 16) |
                ((u64)f2bf(x[2]) << 32) | ((u64)f2bf(x[3]) << 48);
      u64 phi = (u64)f2bf(x[4]) | ((u64)f2bf(x[5]) << 16) |
                ((u64)f2bf(x[6]) << 32) | ((u64)f2bf(x[7]) << 48);
      *reinterpret_cast<u64*>(&Ps[w][qh * 16 + ln][g * 4]) = plo;
      *reinterpret_cast<u64*>(&Ps[w][qh * 16 + ln][16 + g * 4]) = phi;
    }
    asm volatile("s_waitcnt lgkmcnt(0)" ::: "memory");
    bf16x8 pa0 = ld8(&Ps[w][ln][g * 8]);
    bf16x8 pa1 = ld8(&Ps[w][16 + ln][g * 8]);
    // O^T += V^T . P^T
#pragma unroll
    for (int ct = 0; ct < 16; ++ct) {
      bf16x8 vv = *reinterpret_cast<const bf16x8*>(
          Vb + (((ct * 16 + ln) * 64 + g * 16) ^ swz));
      oacc[ct][0] = __builtin_amdgcn_mfma_f32_16x16x32_bf16(vv, pa0, oacc[ct][0], 0, 0, 0);
      oacc[ct][1] = __builtin_amdgcn_mfma_f32_16x16x32_bf16(vv, pa1, oacc[ct][1], 0, 0, 0);
    }
    asm volatile("s_waitcnt vmcnt(0)" ::: "memory");
    __syncthreads();
  }

  // merge key-segments: kseg1 waves -> LDS scratch (aliases stage), kseg0 merges
  float* osc = (float*)&stage[0][0][0][0];  // [qg][d 256][q 32] f32 = 64KB
  if (kseg == 1) {
    if (g == 0) {
#pragma unroll
      for (int qh = 0; qh < 2; ++qh) {
        mls[qg][qh][0][ln] = mrow[qh];
        mls[qg][qh][1][ln] = lrow[qh];
      }
    }
#pragma unroll
    for (int ct = 0; ct < 16; ++ct)
#pragma unroll
      for (int qh = 0; qh < 2; ++qh)
#pragma unroll
        for (int r = 0; r < 4; ++r)
          osc[qg * 8192 + (ct * 16 + g * 4 + r) * 32 + qh * 16 + ln] = oacc[ct][qh][r];
  }
  __syncthreads();
  if (kseg == 0) {
    float wa[2], wb[2], rl[2];
#pragma unroll
    for (int qh = 0; qh < 2; ++qh) {
      float mb = mls[qg][qh][0][ln], lb = mls[qg][qh][1][ln];
      float M = fmaxf(mrow[qh], mb);
      wa[qh] = __expf(mrow[qh] - M);
      wb[qh] = __expf(mb - M);
      rl[qh] = 1.f / (wa[qh] * lrow[qh] + wb[qh] * lb);
    }
#pragma unroll
    for (int ct = 0; ct < 16; ++ct)
#pragma unroll
      for (int qh = 0; qh < 2; ++qh) {
        u64 pk = 0;
#pragma unroll
        for (int r = 0; r < 4; ++r) {
          float val = (wa[qh] * oacc[ct][qh][r] +
                       wb[qh] * osc[qg * 8192 + (ct * 16 + g * 4 + r) * 32 + qh * 16 + ln]) *
                      rl[qh];
          pk |= (u64)f2bf(val) << (16 * r);
        }
        *reinterpret_cast<u64*>(O + ((long)z * N + qbase + qh * 16 + ln) * 256 +
                                ct * 16 + g * 4) = pk;
      }
  }
}

// ---------------- fused q bias: qeb = q_w @ vp_b + q_b ----------------
__global__ __launch_bounds__(256) void qeb_k(const float* __restrict__ qw,
                                             const float* __restrict__ qb, Ptrs4 vpb,
                                             float* __restrict__ qeb) {
  int o = threadIdx.x;
  int lvl = blockIdx.x;
  const float* vb = vpb.p[lvl];
  float acc = qb[o];
  for (int k = 0; k < 256; ++k) acc += qw[o * 256 + k] * vb[k];
  qeb[lvl * 256 + o] = acc;
}

// ---------------- pooling: t levels -> poolT [b][64 pix][1024 ch] bf16 ----------------
__global__ __launch_bounds__(256) void pool_k(Ptrs4 ts, u16* __restrict__ poolT) {
  int gt = blockIdx.x * 256 + threadIdx.x;
  int ch = gt & 1023;
  int pix = (gt >> 10) & 63;
  int b = gt >> 16;
  int level = ch >> 8, c = ch & 255;
  int H = 64 >> level;
  int f = H >> 3;
  int py = pix >> 3, px = pix & 7;
  const float* src = ts.p[level] + (((long)b * 256 + c) * H + py * f) * H + px * f;
  float s = 0.f;
  for (int dy = 0; dy < f; ++dy)
    for (int dx = 0; dx < f; ++dx) s += src[dy * H + dx];
  poolT[gt] = f2bf(s / (float)(f * f));
}

// ---------------- BN(train) + relu + GAP : x[4][256][64] -> xp[4][256] ----------------
__global__ __launch_bounds__(64) void bn_k(const float* __restrict__ x,
                                           const float* __restrict__ gw,
                                           const float* __restrict__ gb,
                                           float* __restrict__ xp) {
  int ch = blockIdx.x, t = threadIdx.x;
  float v[4], s = 0.f, sq = 0.f;
#pragma unroll
  for (int b = 0; b < 4; ++b) {
    v[b] = x[((long)b * 256 + ch) * 64 + t];
    s += v[b];
    sq += v[b] * v[b];
  }
#pragma unroll
  for (int off = 32; off; off >>= 1) {
    s += __shfl_xor(s, off);
    sq += __shfl_xor(sq, off);
  }
  float mu = s * (1.f / 256.f);
  float var = sq * (1.f / 256.f) - mu * mu;
  float rstd = rsqrtf(var + 1e-5f);
  float G = gw[ch], Bb = gb[ch];
#pragma unroll
  for (int b = 0; b < 4; ++b) {
    float y = fmaxf((v[b] - mu) * rstd * G + Bb, 0.f);
#pragma unroll
    for (int off = 32; off; off >>= 1) y += __shfl_xor(y, off);
    if (t == 0) xp[b * 256 + ch] = y * (1.f / 64.f);
  }
}

__global__ __launch_bounds__(256) void fc1_k(const float* __restrict__ xp,
                                             const float* __restrict__ w,
                                             const float* __restrict__ bias,
                                             float* __restrict__ o1) {
  int gt = blockIdx.x * 256 + threadIdx.x;  // 4096 = [b][1024]
  int b = gt >> 10, j = gt & 1023;
  float acc = bias[j];
  const float* wr = w + (long)j * 256;
  const float* xr = xp + b * 256;
  for (int k = 0; k < 256; ++k) acc += xr[k] * wr[k];
  o1[gt] = fmaxf(acc, 0.f);
}

__global__ __launch_bounds__(256) void fc2_k(const float* __restrict__ o1,
                                             const float* __restrict__ w,
                                             const float* __restrict__ bias,
                                             float* __restrict__ out) {
  int gt = blockIdx.x * 256 + threadIdx.x;  // 8192 = [b][2048]
  int b = gt >> 11, o = gt & 2047;
  float acc = bias[o];
  const float* wr = w + (long)o * 1024;
  const float* xr = o1 + b * 1024;
  for (int k = 0; k < 1024; ++k) acc += xr[k] * wr[k];
  out[gt] = acc;
}

extern "C" void kernel_launch(void* const* d_in, const int* in_sizes, int n_in,
                              void* d_out, int out_size, void* d_ws, size_t ws_size,
                              hipStream_t stream) {
  (void)in_sizes; (void)n_in; (void)out_size; (void)ws_size;
  const float *v_in[4], *t_in[4], *vp_w[4], *vp_b[4], *op_w[4], *op_b[4];
  for (int i = 0; i < 4; ++i) {
    v_in[i] = (const float*)d_in[i];
    t_in[i] = (const float*)d_in[4 + i];
    vp_w[i] = (const float*)d_in[8 + 4 * i];
    vp_b[i] = (const float*)d_in[9 + 4 * i];
    op_w[i] = (const float*)d_in[10 + 4 * i];
    op_b[i] = (const float*)d_in[11 + 4 * i];
  }
  const float* q_w = (const float*)d_in[24];
  const float* q_b = (const float*)d_in[25];
  const float* k_w = (const float*)d_in[26];
  const float* k_b = (const float*)d_in[27];
  const float* v_w = (const float*)d_in[28];
  const float* v_b = (const float*)d_in[29];
  const float* sg_w = (const float*)d_in[30];
  const float* sg_b = (const float*)d_in[31];
  const float* bn_g = (const float*)d_in[32];
  const float* bn_b = (const float*)d_in[33];
  const float* fc1_w = (const float*)d_in[34];
  const float* fc1_b = (const float*)d_in[35];
  const float* fc2_w = (const float*)d_in[36];
  const float* fc2_b = (const float*)d_in[37];
  float* out = (float*)d_out;

  const int cin[4] = {64, 128, 256, 512};
  const int NN[4] = {4096, 1024, 256, 64};

  char* ws = (char*)d_ws;
  size_t off = 0;
  auto alloc = [&](size_t bytes) {
    void* p = ws + off;
    off += (bytes + 255) & ~(size_t)255;
    return p;
  };
  u16* w_q = (u16*)alloc(65536 * 2);
  u16* w_kv = (u16*)alloc(131072 * 2);
  u16* w_op[4];
  for (int i = 0; i < 4; ++i) w_op[i] = (u16*)alloc((size_t)cin[i] * 256 * 2);
  u16* w_sg = (u16*)alloc(262144 * 2);
  u16* vpwT[4];
  for (int i = 0; i < 4; ++i) vpwT[i] = (u16*)alloc((size_t)cin[i] * 256 * 2);
  u16* qe[4];
  for (int i = 0; i < 4; ++i) qe[i] = (u16*)alloc((size_t)256 * cin[i] * 2);
  float* qeb = (float*)alloc(1024 * 4);
  u16* vT = (u16*)alloc((size_t)4 * 4096 * 64 * 2);
  u16* tT = (u16*)alloc((size_t)4 * 4096 * 256 * 2);
  u16* QT = (u16*)alloc((size_t)4 * 4096 * 256 * 2);
  u16* Kt = (u16*)alloc((size_t)4 * 4096 * 256 * 2);
  u16* Vt = (u16*)alloc((size_t)4 * 4096 * 256 * 2);
  u16* Ob = (u16*)alloc((size_t)4 * 4096 * 256 * 2);
  u16* poolT = (u16*)alloc((size_t)262144 * 2);
  float* xbuf = (float*)alloc((size_t)65536 * 4);
  float* xp = (float*)alloc(1024 * 4);
  float* fc1o = (float*)alloc(4096 * 4);

  // weights -> bf16
  CvtJobs jobs;
  jobs.j[0] = {q_w, w_q, 65536};
  jobs.j[1] = {k_w, w_kv, 65536};
  jobs.j[2] = {v_w, w_kv + 65536, 65536};
  jobs.j[3] = {op_w[0], w_op[0], cin[0] * 256};
  jobs.j[4] = {op_w[1], w_op[1], cin[1] * 256};
  jobs.j[5] = {op_w[2], w_op[2], cin[2] * 256};
  jobs.j[6] = {op_w[3], w_op[3], cin[3] * 256};
  jobs.j[7] = {sg_w, w_sg, 262144};
  cvt_multi<<<dim3(32, 8), 256, 0, stream>>>(jobs);

  // fused qe = q_w @ vp_w  (and fused bias)
  for (int i = 0; i < 4; ++i)
    transpose_cvt<<<dim3(cin[i] / 32, 8, 1), 256, 0, stream>>>(vp_w[i], vpwT[i], 256, cin[i]);
  for (int i = 0; i < 4; ++i)
    gemm_k<1><<<dim3(cin[i] / 64, 4, 1), 256, 0, stream>>>(
        w_q, vpwT[i], nullptr, nullptr, qe[i], nullptr, nullptr, 256, cin[i], 256);
  Ptrs4 vpbp;
  for (int i = 0; i < 4; ++i) vpbp.p[i] = vp_b[i];
  qeb_k<<<4, 256, 0, stream>>>(q_w, q_b, vpbp, qeb);

  const long enh_off[4] = {8192, 8192 + 1048576, 8192 + 1048576 + 524288,
                           8192 + 1048576 + 524288 + 262144};

  for (int i = 0; i < 4; ++i) {
    int N = NN[i], C = cin[i];
    transpose_cvt<<<dim3(N / 32, C / 32, 4), 256, 0, stream>>>(v_in[i], vT, C, N);
    transpose_cvt<<<dim3(N / 32, 8, 4), 256, 0, stream>>>(t_in[i], tT, 256, N);
    // Q = qe @ v + qeb   -> QT [z][N][256]
    gemm_k<0><<<dim3(N / 64, 4, 4), 256, 0, stream>>>(
        qe[i], vT, qeb + 256 * i, nullptr, QT, nullptr, nullptr, 256, N, C);
    // K,V from t -> swizzled key-tiles Kt, Vt
    gemm_k<3><<<dim3(N / 64, 8, 4), 256, 0, stream>>>(
        w_kv, tT, k_b, v_b, Kt, Vt, nullptr, 512, N, 256);
    attn_k<<<dim3(N / 64, 4), 256, 0, stream>>>(QT, Kt, Vt, Ob, N);
    // enhanced = op_w @ O^T + op_b + v  -> d_out
    gemm_k<2><<<dim3(N / 64, C / 64, 4), 256, 0, stream>>>(
        w_op[i], Ob, op_b[i], nullptr, out + enh_off[i], nullptr, v_in[i], C, N, 256);
  }

  // semantic branch
  Ptrs4 tp;
  for (int i = 0; i < 4; ++i) tp.p[i] = t_in[i];
  pool_k<<<1024, 256, 0, stream>>>(tp, poolT);
  gemm_k<2><<<dim3(1, 4, 4), 256, 0, stream>>>(
      w_sg, poolT, sg_b, nullptr, xbuf, nullptr, nullptr, 256, 64, 1024);
  bn_k<<<256, 64, 0, stream>>>(xbuf, bn_g, bn_b, xp);
  fc1_k<<<16, 256, 0, stream>>>(xp, fc1_w, fc1_b, fc1o);
  fc2_k<<<32, 256, 0, stream>>>(fc1o, fc2_w, fc2_b, out);
}

// Round 9
// 458.350 us; speedup vs baseline: 1.1966x; 1.1966x over previous
//
#include <hip/hip_runtime.h>

typedef __bf16 bf16_t;
typedef bf16_t bf16x8 __attribute__((ext_vector_type(8)));
typedef float f32x4 __attribute__((ext_vector_type(4)));
typedef unsigned short u16;
typedef unsigned long long u64;

__device__ __forceinline__ u16 f2bf(float f) {
  union { float f; unsigned u; } v; v.f = f;
  unsigned r = v.u + 0x7FFFu + ((v.u >> 16) & 1u);
  return (u16)(r >> 16);
}
__device__ __forceinline__ bf16x8 ld8(const u16* p) {
  return *reinterpret_cast<const bf16x8*>(p);
}
__device__ __forceinline__ void gload_lds16(const void* g, void* l) {
  __builtin_amdgcn_global_load_lds(
      (const __attribute__((address_space(1))) void*)g,
      (__attribute__((address_space(3))) void*)l, 16, 0, 0);
}

struct Ptrs4 { const float* p[4]; };

// ---------------- f32 -> bf16 conversions ----------------
struct CvtJob { const float* s; u16* d; int n; };
struct CvtJobs { CvtJob j[8]; };

__global__ __launch_bounds__(256) void cvt_multi(CvtJobs jobs) {
  CvtJob J = jobs.j[blockIdx.y];
  for (int i = blockIdx.x * 256 + threadIdx.x; i < J.n; i += gridDim.x * 256)
    J.d[i] = f2bf(J.s[i]);
}

// ---------------- batched transpose: in [z][C][N] f32 -> out [z][N][C] bf16 ----
struct TJob { const float* s; u16* d; int C, N, nbx, nbz, off; };
struct TJobs { TJob j[12]; };

__global__ __launch_bounds__(256) void transpose_batch(TJobs J, int nj) {
  int bid = blockIdx.x, ji = 0;
#pragma unroll
  for (int k = 1; k < 12; ++k)
    if (k < nj && bid >= J.j[k].off) ji = k;
  TJob job = J.j[ji];
  int local = bid - job.off;
  int z = local % job.nbz;
  int l2 = local / job.nbz;
  int bx = l2 % job.nbx, by = l2 / job.nbx;
  __shared__ float t[32][33];
  int tx = threadIdx.x & 31, ty = threadIdx.x >> 5;
  int n0 = bx * 32, c0 = by * 32;
  long zi = (long)z * job.C * job.N, zo = (long)z * job.N * job.C;
#pragma unroll
  for (int i = 0; i < 4; ++i)
    t[ty + 8 * i][tx] = job.s[zi + (long)(c0 + ty + 8 * i) * job.N + n0 + tx];
  __syncthreads();
#pragma unroll
  for (int i = 0; i < 4; ++i)
    job.d[zo + (long)(n0 + ty + 8 * i) * job.C + c0 + tx] = f2bf(t[tx][ty + 8 * i]);
}

// ---------------- batched GEMM: C[m][n] = sum_k A[m][k]*X[z][n][k] (+bias[m]) ----
// MODE 0: o1 bf16 [z][N][M] (transposed store)
// MODE 1: o1 bf16 [z][M][N]
// MODE 2: o1 f32  [z][M][N], bias + optional residual res
// MODE 3: KV: rows<256 -> o1 = K swizzled 16KB key-tiles [z][N/32]{[32][256] ^((key&7)<<4)}
//             rows>=256 -> o2 = V plain key-tiles [z][N/32][256][32]
struct GJob {
  const u16 *A, *X;
  const float *bias, *bias2;
  void *o1, *o2;
  const float* res;
  int M, N, K, nbx, nbz, off;
};
struct GJobs { GJob j[5]; };

template <int MODE>
__global__ __launch_bounds__(256) void gemm_batch(GJobs J, int nj) {
  int bid = blockIdx.x, ji = 0;
#pragma unroll
  for (int k = 1; k < 5; ++k)
    if (k < nj && bid >= J.j[k].off) ji = k;
  GJob job = J.j[ji];
  int local = bid - job.off;
  const int z = local % job.nbz;
  int l2 = local / job.nbz;
  const int n0 = (l2 % job.nbx) * 64, m0 = (l2 / job.nbx) * 64;
  const int M = job.M, N = job.N, K = job.K;
  const u16* __restrict__ A = job.A;
  const u16* __restrict__ X = job.X;

  __shared__ __attribute__((aligned(16))) u16 As[64][40];
  __shared__ __attribute__((aligned(16))) u16 Bs[64][40];
  const int tid = threadIdx.x;
  const long Xz = (long)z * N * K;
  const int arow = tid >> 2, acol = (tid & 3) * 8;
  const int w = tid >> 6, lane = tid & 63, g = lane >> 4, ln = lane & 15;
  const int wm = (w >> 1) * 32, wn = (w & 1) * 32;
  f32x4 zero = {0.f, 0.f, 0.f, 0.f};
  f32x4 acc[2][2];
#pragma unroll
  for (int i = 0; i < 2; ++i)
#pragma unroll
    for (int j = 0; j < 2; ++j) acc[i][j] = zero;

  for (int k0 = 0; k0 < K; k0 += 32) {
    int4 av = *reinterpret_cast<const int4*>(A + (long)(m0 + arow) * K + k0 + acol);
    int4 bv = *reinterpret_cast<const int4*>(X + Xz + (long)(n0 + arow) * K + k0 + acol);
    __syncthreads();
    *reinterpret_cast<int4*>(&As[arow][acol]) = av;
    *reinterpret_cast<int4*>(&Bs[arow][acol]) = bv;
    __syncthreads();
    bf16x8 a0 = ld8(&As[wm + ln][g * 8]);
    bf16x8 a1 = ld8(&As[wm + 16 + ln][g * 8]);
    bf16x8 b0 = ld8(&Bs[wn + ln][g * 8]);
    bf16x8 b1 = ld8(&Bs[wn + 16 + ln][g * 8]);
    acc[0][0] = __builtin_amdgcn_mfma_f32_16x16x32_bf16(a0, b0, acc[0][0], 0, 0, 0);
    acc[0][1] = __builtin_amdgcn_mfma_f32_16x16x32_bf16(a0, b1, acc[0][1], 0, 0, 0);
    acc[1][0] = __builtin_amdgcn_mfma_f32_16x16x32_bf16(a1, b0, acc[1][0], 0, 0, 0);
    acc[1][1] = __builtin_amdgcn_mfma_f32_16x16x32_bf16(a1, b1, acc[1][1], 0, 0, 0);
  }

#pragma unroll
  for (int i = 0; i < 2; ++i) {
#pragma unroll
    for (int j = 0; j < 2; ++j) {
      int mr0 = m0 + wm + 16 * i + g * 4;
      int nc = n0 + wn + 16 * j + ln;
      if (MODE == 0) {
        u64 pk = 0;
#pragma unroll
        for (int r = 0; r < 4; ++r) {
          float val = acc[i][j][r] + (job.bias ? job.bias[mr0 + r] : 0.f);
          pk |= (u64)f2bf(val) << (16 * r);
        }
        *reinterpret_cast<u64*>((u16*)job.o1 + ((long)z * N + nc) * M + mr0) = pk;
      } else if (MODE == 1) {
#pragma unroll
        for (int r = 0; r < 4; ++r) {
          float val = acc[i][j][r] + (job.bias ? job.bias[mr0 + r] : 0.f);
          ((u16*)job.o1)[((long)z * M + mr0 + r) * N + nc] = f2bf(val);
        }
      } else if (MODE == 2) {
#pragma unroll
        for (int r = 0; r < 4; ++r) {
          long idx = ((long)z * M + mr0 + r) * N + nc;
          float val = acc[i][j][r] + job.bias[mr0 + r];
          if (job.res) val += job.res[idx];
          ((float*)job.o1)[idx] = val;
        }
      } else {
        long tbase = (long)z * N * 256 + (long)(nc >> 5) * 8192;  // u16 elems
        if (mr0 < 256) {
          // K tile: [key 32][ch 256] bf16, byte ^= ((key&7)<<4)
          u64 pk = 0;
#pragma unroll
          for (int r = 0; r < 4; ++r)
            pk |= (u64)f2bf(acc[i][j][r] + job.bias[mr0 + r]) << (16 * r);
          int byteoff = ((nc & 31) * 512 + mr0 * 2) ^ ((nc & 7) << 4);
          *reinterpret_cast<u64*>((char*)job.o1 + tbase * 2 + byteoff) = pk;
        } else {
          // V tile: [d 256][key 32] bf16, plain (read direct from global)
          int d0 = mr0 - 256;
#pragma unroll
          for (int r = 0; r < 4; ++r)
            ((u16*)job.o2)[tbase + (long)(d0 + r) * 32 + (nc & 31)] =
                f2bf(acc[i][j][r] + job.bias2[d0 + r]);
        }
      }
    }
  }
}

// ---------------- batched flash attention ------------------------------------
// Q: [z][N][256] bf16; K: swizzled 16KB key-tiles; V: plain key-tiles [256][32];
// O: [z][N][256] bf16. Block 256 thr = 4 waves: qg=w&1 (32 q), kseg=w>>1.
// K double-buffered in LDS via global_load_lds; V read direct global->reg.
struct AJob { const u16 *Q, *K, *V; u16* O; int N, off; };
struct AJobs { AJob j[4]; };

__global__ __launch_bounds__(256, 2) void attn_batch(AJobs J, int nj) {
  __shared__ __attribute__((aligned(16))) char stK[2][2][16384];
  __shared__ __attribute__((aligned(16))) u16 Ps[4][32][40];
  __shared__ float mls[2][2][2][16];
  int bid = blockIdx.x, ji = 0;
#pragma unroll
  for (int k = 1; k < 4; ++k)
    if (k < nj && bid >= J.j[k].off) ji = k;
  AJob job = J.j[ji];
  int local = bid - job.off;
  const int z = local & 3, bx = local >> 2;  // z fastest: pins z to XCD pairs
  const int N = job.N;
  const int tid = threadIdx.x;
  const int w = tid >> 6, lane = tid & 63;
  const int g = lane >> 4, ln = lane & 15;
  const int qg = w & 1, kseg = w >> 1;
  const int qbase = bx * 64 + qg * 32;
  const float scale = 0.0625f;  // 1/sqrt(256)
  const int nt = N >> 6;        // 32-key tiles per kseg
  const long tb = (long)z * (N >> 5) + (long)kseg * nt;

  // Q as B-fragments: qf[qh][cc], col = query = ln within half qh
  bf16x8 qf[2][8];
#pragma unroll
  for (int qh = 0; qh < 2; ++qh) {
    const u16* qp = job.Q + ((long)z * N + qbase + qh * 16 + ln) * 256 + g * 8;
#pragma unroll
    for (int cc = 0; cc < 8; ++cc) qf[qh][cc] = ld8(qp + cc * 32);
  }
  f32x4 zero = {0.f, 0.f, 0.f, 0.f};
  f32x4 oacc[16][2];
#pragma unroll
  for (int ct = 0; ct < 16; ++ct) {
    oacc[ct][0] = zero;
    oacc[ct][1] = zero;
  }
  float mrow[2] = {-1e30f, -1e30f}, lrow[2] = {0.f, 0.f};

  // wave (kseg,qg) stages half (8KB) of its kseg's K tile
  auto stage_K = [&](int buf, int t) {
    const char* gp = (const char*)job.K + (tb + t) * 16384 + qg * 8192 + lane * 16;
    char* lp = &stK[buf][kseg][qg * 8192];
#pragma unroll
    for (int q = 0; q < 8; ++q) gload_lds16(gp + q * 1024, lp + q * 1024);
  };

  stage_K(0, 0);
  asm volatile("s_waitcnt vmcnt(0)" ::: "memory");
  __syncthreads();

  const int swz = (ln & 7) << 4;
  for (int t = 0; t < nt; ++t) {
    const int buf = t & 1;
    if (t + 1 < nt) stage_K(buf ^ 1, t + 1);
    const char* Kb = &stK[buf][kseg][0];
    const u16* Vg = job.V + (tb + t) * 8192;

    // S^T = K . Q^T : s[kh][qh], lane col = query ln, rows = keys
    f32x4 s[2][2];
    s[0][0] = zero; s[0][1] = zero; s[1][0] = zero; s[1][1] = zero;
#pragma unroll
    for (int cc = 0; cc < 8; ++cc) {
      bf16x8 k0 = *reinterpret_cast<const bf16x8*>(Kb + ((ln * 512 + cc * 64 + g * 16) ^ swz));
      bf16x8 k1 = *reinterpret_cast<const bf16x8*>(Kb + (((16 + ln) * 512 + cc * 64 + g * 16) ^ swz));
      s[0][0] = __builtin_amdgcn_mfma_f32_16x16x32_bf16(k0, qf[0][cc], s[0][0], 0, 0, 0);
      s[0][1] = __builtin_amdgcn_mfma_f32_16x16x32_bf16(k0, qf[1][cc], s[0][1], 0, 0, 0);
      s[1][0] = __builtin_amdgcn_mfma_f32_16x16x32_bf16(k1, qf[0][cc], s[1][0], 0, 0, 0);
      s[1][1] = __builtin_amdgcn_mfma_f32_16x16x32_bf16(k1, qf[1][cc], s[1][1], 0, 0, 0);
    }
    // issue V batch 1 early (hides L2 latency under softmax)
    bf16x8 vv[8];
#pragma unroll
    for (int ct = 0; ct < 8; ++ct) vv[ct] = ld8(Vg + (ct * 16 + ln) * 32 + g * 8);

#pragma unroll
    for (int qh = 0; qh < 2; ++qh) {
      float x[8];
#pragma unroll
      for (int r = 0; r < 4; ++r) { x[r] = s[0][qh][r] * scale; x[4 + r] = s[1][qh][r] * scale; }
      float lm = fmaxf(fmaxf(fmaxf(x[0], x[1]), fmaxf(x[2], x[3])),
                       fmaxf(fmaxf(x[4], x[5]), fmaxf(x[6], x[7])));
      lm = fmaxf(lm, __shfl_xor(lm, 16));
      lm = fmaxf(lm, __shfl_xor(lm, 32));
      if (!__all(lm - mrow[qh] <= 8.0f)) {  // T13 defer-max
        float nm = fmaxf(mrow[qh], lm);
        float fac = __expf(mrow[qh] - nm);
        mrow[qh] = nm;
        lrow[qh] *= fac;
#pragma unroll
        for (int ct = 0; ct < 16; ++ct)
#pragma unroll
          for (int r = 0; r < 4; ++r) oacc[ct][qh][r] *= fac;
      }
      float ps = 0.f;
#pragma unroll
      for (int j2 = 0; j2 < 8; ++j2) { x[j2] = __expf(x[j2] - mrow[qh]); ps += x[j2]; }
      ps += __shfl_xor(ps, 16);
      ps += __shfl_xor(ps, 32);
      lrow[qh] += ps;
      u64 plo = (u64)f2bf(x[0]) | ((u64)f2bf(x[1]) << 16) |
                ((u64)f2bf(x[2]) << 32) | ((u64)f2bf(x[3]) << 48);
      u64 phi = (u64)f2bf(x[4]) | ((u64)f2bf(x[5]) << 16) |
                ((u64)f2bf(x[6]) << 32) | ((u64)f2bf(x[7]) << 48);
      *reinterpret_cast<u64*>(&Ps[w][qh * 16 + ln][g * 4]) = plo;
      *reinterpret_cast<u64*>(&Ps[w][qh * 16 + ln][16 + g * 4]) = phi;
    }
    asm volatile("s_waitcnt lgkmcnt(0)" ::: "memory");
    bf16x8 pa0 = ld8(&Ps[w][ln][g * 8]);
    bf16x8 pa1 = ld8(&Ps[w][16 + ln][g * 8]);
    // O^T += V^T . P^T  (two V batches to bound register pressure)
#pragma unroll
    for (int ct = 0; ct < 8; ++ct) {
      oacc[ct][0] = __builtin_amdgcn_mfma_f32_16x16x32_bf16(vv[ct], pa0, oacc[ct][0], 0, 0, 0);
      oacc[ct][1] = __builtin_amdgcn_mfma_f32_16x16x32_bf16(vv[ct], pa1, oacc[ct][1], 0, 0, 0);
    }
#pragma unroll
    for (int ct = 0; ct < 8; ++ct) vv[ct] = ld8(Vg + ((ct + 8) * 16 + ln) * 32 + g * 8);
#pragma unroll
    for (int ct = 0; ct < 8; ++ct) {
      oacc[ct + 8][0] = __builtin_amdgcn_mfma_f32_16x16x32_bf16(vv[ct], pa0, oacc[ct + 8][0], 0, 0, 0);
      oacc[ct + 8][1] = __builtin_amdgcn_mfma_f32_16x16x32_bf16(vv[ct], pa1, oacc[ct + 8][1], 0, 0, 0);
    }
    asm volatile("s_waitcnt vmcnt(0)" ::: "memory");
    __syncthreads();
  }

  // merge key-segments: kseg1 waves -> LDS scratch (aliases stK), kseg0 merges
  float* osc = (float*)&stK[0][0][0];  // [qg 2][d 256][q 32] f32 = 64KB
  if (kseg == 1) {
    if (g == 0) {
#pragma unroll
      for (int qh = 0; qh < 2; ++qh) {
        mls[qg][qh][0][ln] = mrow[qh];
        mls[qg][qh][1][ln] = lrow[qh];
      }
    }
#pragma unroll
    for (int ct = 0; ct < 16; ++ct)
#pragma unroll
      for (int qh = 0; qh < 2; ++qh)
#pragma unroll
        for (int r = 0; r < 4; ++r)
          osc[qg * 8192 + (ct * 16 + g * 4 + r) * 32 + qh * 16 + ln] = oacc[ct][qh][r];
  }
  __syncthreads();
  if (kseg == 0) {
    float wa[2], wb[2], rl[2];
#pragma unroll
    for (int qh = 0; qh < 2; ++qh) {
      float mb = mls[qg][qh][0][ln], lb = mls[qg][qh][1][ln];
      float M = fmaxf(mrow[qh], mb);
      wa[qh] = __expf(mrow[qh] - M);
      wb[qh] = __expf(mb - M);
      rl[qh] = 1.f / (wa[qh] * lrow[qh] + wb[qh] * lb);
    }
#pragma unroll
    for (int ct = 0; ct < 16; ++ct)
#pragma unroll
      for (int qh = 0; qh < 2; ++qh) {
        u64 pk = 0;
#pragma unroll
        for (int r = 0; r < 4; ++r) {
          float val = (wa[qh] * oacc[ct][qh][r] +
                       wb[qh] * osc[qg * 8192 + (ct * 16 + g * 4 + r) * 32 + qh * 16 + ln]) *
                      rl[qh];
          pk |= (u64)f2bf(val) << (16 * r);
        }
        *reinterpret_cast<u64*>(job.O + ((long)z * N + qbase + qh * 16 + ln) * 256 +
                                ct * 16 + g * 4) = pk;
      }
  }
}

// ---------------- fused q bias: qeb = q_w @ vp_b + q_b ----------------
__global__ __launch_bounds__(256) void qeb_k(const float* __restrict__ qw,
                                             const float* __restrict__ qb, Ptrs4 vpb,
                                             float* __restrict__ qeb) {
  int o = threadIdx.x;
  int lvl = blockIdx.x;
  const float* vb = vpb.p[lvl];
  float acc = qb[o];
  for (int k = 0; k < 256; ++k) acc += qw[o * 256 + k] * vb[k];
  qeb[lvl * 256 + o] = acc;
}

// ---------------- pooling: t levels -> poolT [b][64 pix][1024 ch] bf16 --------
__global__ __launch_bounds__(256) void pool_k(Ptrs4 ts, u16* __restrict__ poolT) {
  int gt = blockIdx.x * 256 + threadIdx.x;
  int ch = gt & 1023;
  int pix = (gt >> 10) & 63;
  int b = gt >> 16;
  int level = ch >> 8, c = ch & 255;
  int H = 64 >> level;
  int f = H >> 3;
  int py = pix >> 3, px = pix & 7;
  const float* src = ts.p[level] + (((long)b * 256 + c) * H + py * f) * H + px * f;
  float s = 0.f;
  for (int dy = 0; dy < f; ++dy)
    for (int dx = 0; dx < f; ++dx) s += src[dy * H + dx];
  poolT[gt] = f2bf(s / (float)(f * f));
}

// ---------------- BN(train) + relu + GAP : x[4][256][64] -> xp[4][256] --------
__global__ __launch_bounds__(64) void bn_k(const float* __restrict__ x,
                                           const float* __restrict__ gw,
                                           const float* __restrict__ gb,
                                           float* __restrict__ xp) {
  int ch = blockIdx.x, t = threadIdx.x;
  float v[4], s = 0.f, sq = 0.f;
#pragma unroll
  for (int b = 0; b < 4; ++b) {
    v[b] = x[((long)b * 256 + ch) * 64 + t];
    s += v[b];
    sq += v[b] * v[b];
  }
#pragma unroll
  for (int off = 32; off; off >>= 1) {
    s += __shfl_xor(s, off);
    sq += __shfl_xor(sq, off);
  }
  float mu = s * (1.f / 256.f);
  float var = sq * (1.f / 256.f) - mu * mu;
  float rstd = rsqrtf(var + 1e-5f);
  float G = gw[ch], Bb = gb[ch];
#pragma unroll
  for (int b = 0; b < 4; ++b) {
    float y = fmaxf((v[b] - mu) * rstd * G + Bb, 0.f);
#pragma unroll
    for (int off = 32; off; off >>= 1) y += __shfl_xor(y, off);
    if (t == 0) xp[b * 256 + ch] = y * (1.f / 64.f);
  }
}

__global__ __launch_bounds__(256) void fc1_k(const float* __restrict__ xp,
                                             const float* __restrict__ w,
                                             const float* __restrict__ bias,
                                             float* __restrict__ o1) {
  int gt = blockIdx.x * 256 + threadIdx.x;  // 4096 = [b][1024]
  int b = gt >> 10, j = gt & 1023;
  float acc = bias[j];
  const float* wr = w + (long)j * 256;
  const float* xr = xp + b * 256;
  for (int k = 0; k < 256; ++k) acc += xr[k] * wr[k];
  o1[gt] = fmaxf(acc, 0.f);
}

__global__ __launch_bounds__(256) void fc2_k(const float* __restrict__ o1,
                                             const float* __restrict__ w,
                                             const float* __restrict__ bias,
                                             float* __restrict__ out) {
  int gt = blockIdx.x * 256 + threadIdx.x;  // 8192 = [b][2048]
  int b = gt >> 11, o = gt & 2047;
  float acc = bias[o];
  const float* wr = w + (long)o * 1024;
  const float* xr = o1 + b * 1024;
  for (int k = 0; k < 1024; ++k) acc += xr[k] * wr[k];
  out[gt] = acc;
}

extern "C" void kernel_launch(void* const* d_in, const int* in_sizes, int n_in,
                              void* d_out, int out_size, void* d_ws, size_t ws_size,
                              hipStream_t stream) {
  (void)in_sizes; (void)n_in; (void)out_size; (void)ws_size;
  const float *v_in[4], *t_in[4], *vp_w[4], *vp_b[4], *op_w[4], *op_b[4];
  for (int i = 0; i < 4; ++i) {
    v_in[i] = (const float*)d_in[i];
    t_in[i] = (const float*)d_in[4 + i];
    vp_w[i] = (const float*)d_in[8 + 4 * i];
    vp_b[i] = (const float*)d_in[9 + 4 * i];
    op_w[i] = (const float*)d_in[10 + 4 * i];
    op_b[i] = (const float*)d_in[11 + 4 * i];
  }
  const float* q_w = (const float*)d_in[24];
  const float* q_b = (const float*)d_in[25];
  const float* k_w = (const float*)d_in[26];
  const float* k_b = (const float*)d_in[27];
  const float* v_w = (const float*)d_in[28];
  const float* v_b = (const float*)d_in[29];
  const float* sg_w = (const float*)d_in[30];
  const float* sg_b = (const float*)d_in[31];
  const float* bn_g = (const float*)d_in[32];
  const float* bn_b = (const float*)d_in[33];
  const float* fc1_w = (const float*)d_in[34];
  const float* fc1_b = (const float*)d_in[35];
  const float* fc2_w = (const float*)d_in[36];
  const float* fc2_b = (const float*)d_in[37];
  float* out = (float*)d_out;

  const int cin[4] = {64, 128, 256, 512};
  const int NN[4] = {4096, 1024, 256, 64};
  // per-level offsets (u16 elems) into the big [all levels][z][N][256] buffers
  const long NOFF[4] = {0, 4194304, 5242880, 5505024};     // 4*N*256 cumsum
  const long VOFF[4] = {0, 1048576, 1572864, 1835008};     // 4*N*cin cumsum

  char* ws = (char*)d_ws;
  size_t off = 0;
  auto alloc = [&](size_t bytes) {
    void* p = ws + off;
    off += (bytes + 255) & ~(size_t)255;
    return p;
  };
  u16* w_q = (u16*)alloc(65536 * 2);
  u16* w_kv = (u16*)alloc(131072 * 2);
  u16* w_op[4];
  for (int i = 0; i < 4; ++i) w_op[i] = (u16*)alloc((size_t)cin[i] * 256 * 2);
  u16* w_sg = (u16*)alloc(262144 * 2);
  u16* vpwT[4];
  for (int i = 0; i < 4; ++i) vpwT[i] = (u16*)alloc((size_t)cin[i] * 256 * 2);
  u16* qe[4];
  for (int i = 0; i < 4; ++i) qe[i] = (u16*)alloc((size_t)256 * cin[i] * 2);
  float* qeb = (float*)alloc(1024 * 4);
  u16* vT = (u16*)alloc((size_t)1966080 * 2);
  u16* tT = (u16*)alloc((size_t)5570560 * 2);
  u16* QT = (u16*)alloc((size_t)5570560 * 2);
  u16* Kt = (u16*)alloc((size_t)5570560 * 2);
  u16* Vt = (u16*)alloc((size_t)5570560 * 2);
  u16* Ob = (u16*)alloc((size_t)5570560 * 2);
  u16* poolT = (u16*)alloc((size_t)262144 * 2);
  float* xbuf = (float*)alloc((size_t)65536 * 4);
  float* xp = (float*)alloc(1024 * 4);
  float* fc1o = (float*)alloc(4096 * 4);

  // 1) weights -> bf16
  CvtJobs jobs;
  jobs.j[0] = {q_w, w_q, 65536};
  jobs.j[1] = {k_w, w_kv, 65536};
  jobs.j[2] = {v_w, w_kv + 65536, 65536};
  jobs.j[3] = {op_w[0], w_op[0], cin[0] * 256};
  jobs.j[4] = {op_w[1], w_op[1], cin[1] * 256};
  jobs.j[5] = {op_w[2], w_op[2], cin[2] * 256};
  jobs.j[6] = {op_w[3], w_op[3], cin[3] * 256};
  jobs.j[7] = {sg_w, w_sg, 262144};
  cvt_multi<<<dim3(32, 8), 256, 0, stream>>>(jobs);

  // 2) batched transposes: vp_w (4), v (4), t (4)
  {
    TJobs T;
    int boff = 0, nj = 0;
    for (int i = 0; i < 4; ++i) {  // vp_w: [256][cin] -> [cin][256]
      int nbx = cin[i] / 32;
      T.j[nj] = {vp_w[i], vpwT[i], 256, cin[i], nbx, 1, boff};
      boff += nbx * 8;
      ++nj;
    }
    for (int i = 0; i < 4; ++i) {  // v: [z][cin][N] -> [z][N][cin]
      int nbx = NN[i] / 32, nby = cin[i] / 32;
      T.j[nj] = {v_in[i], vT + VOFF[i], cin[i], NN[i], nbx, 4, boff};
      boff += nbx * nby * 4;
      ++nj;
    }
    for (int i = 0; i < 4; ++i) {  // t: [z][256][N] -> [z][N][256]
      int nbx = NN[i] / 32;
      T.j[nj] = {t_in[i], tT + NOFF[i], 256, NN[i], nbx, 4, boff};
      boff += nbx * 8 * 4;
      ++nj;
    }
    transpose_batch<<<boff, 256, 0, stream>>>(T, nj);
  }

  // 3) qe = q_w @ vp_w (4 jobs, MODE 1)
  {
    GJobs G;
    int boff = 0;
    for (int i = 0; i < 4; ++i) {
      int nbx = cin[i] / 64;
      G.j[i] = {w_q, vpwT[i], nullptr, nullptr, qe[i], nullptr, nullptr,
                256, cin[i], 256, nbx, 1, boff};
      boff += nbx * 4;
    }
    gemm_batch<1><<<boff, 256, 0, stream>>>(G, 4);
  }
  Ptrs4 vpbp;
  for (int i = 0; i < 4; ++i) vpbp.p[i] = vp_b[i];
  qeb_k<<<4, 256, 0, stream>>>(q_w, q_b, vpbp, qeb);

  // 4) Q = qe @ v + qeb (4 jobs, MODE 0)
  {
    GJobs G;
    int boff = 0;
    for (int i = 0; i < 4; ++i) {
      int nbx = NN[i] / 64;
      G.j[i] = {qe[i], vT + VOFF[i], qeb + 256 * i, nullptr, QT + NOFF[i], nullptr,
                nullptr, 256, NN[i], cin[i], nbx, 4, boff};
      boff += nbx * 4 * 4;
    }
    gemm_batch<0><<<boff, 256, 0, stream>>>(G, 4);
  }

  // 5) K,V from t (4 jobs, MODE 3)
  {
    GJobs G;
    int boff = 0;
    for (int i = 0; i < 4; ++i) {
      int nbx = NN[i] / 64;
      G.j[i] = {w_kv, tT + NOFF[i], k_b, v_b, Kt + NOFF[i], Vt + NOFF[i], nullptr,
                512, NN[i], 256, nbx, 4, boff};
      boff += nbx * 8 * 4;
    }
    gemm_batch<3><<<boff, 256, 0, stream>>>(G, 4);
  }

  // 6) attention (4 jobs)
  {
    AJobs A;
    int boff = 0;
    for (int i = 0; i < 4; ++i) {
      A.j[i] = {QT + NOFF[i], Kt + NOFF[i], Vt + NOFF[i], Ob + NOFF[i], NN[i], boff};
      boff += (NN[i] / 64) * 4;
    }
    attn_batch<<<boff, 256, 0, stream>>>(A, 4);
  }

  // 7) pooling for semantic branch
  Ptrs4 tp;
  for (int i = 0; i < 4; ++i) tp.p[i] = t_in[i];
  pool_k<<<1024, 256, 0, stream>>>(tp, poolT);

  // 8) op-proj + residual (4 jobs) and sg-gemm (1 job), MODE 2
  const long enh_off[4] = {8192, 8192 + 1048576, 8192 + 1048576 + 524288,
                           8192 + 1048576 + 524288 + 262144};
  {
    GJobs G;
    int boff = 0;
    for (int i = 0; i < 4; ++i) {
      int nbx = NN[i] / 64, nby = cin[i] / 64;
      G.j[i] = {w_op[i], Ob + NOFF[i], op_b[i], nullptr, out + enh_off[i], nullptr,
                v_in[i], cin[i], NN[i], 256, nbx, 4, boff};
      boff += nbx * nby * 4;
    }
    G.j[4] = {w_sg, poolT, sg_b, nullptr, xbuf, nullptr, nullptr,
              256, 64, 1024, 1, 4, boff};
    boff += 1 * 4 * 4;
    gemm_batch<2><<<boff, 256, 0, stream>>>(G, 5);
  }

  // 9) semantic tail
  bn_k<<<256, 64, 0, stream>>>(xbuf, bn_g, bn_b, xp);
  fc1_k<<<16, 256, 0, stream>>>(xp, fc1_w, fc1_b, fc1o);
  fc2_k<<<32, 256, 0, stream>>>(fc1o, fc2_w, fc2_b, out);
}

// Round 10
// 378.724 us; speedup vs baseline: 1.4482x; 1.2102x over previous
//
#include <hip/hip_runtime.h>

typedef __bf16 bf16_t;
typedef bf16_t bf16x8 __attribute__((ext_vector_type(8)));
typedef float f32x4 __attribute__((ext_vector_type(4)));
typedef unsigned short u16;
typedef unsigned long long u64;

__device__ __forceinline__ u16 f2bf(float f) {
  union { float f; unsigned u; } v; v.f = f;
  unsigned r = v.u + 0x7FFFu + ((v.u >> 16) & 1u);
  return (u16)(r >> 16);
}
__device__ __forceinline__ bf16x8 ld8(const u16* p) {
  return *reinterpret_cast<const bf16x8*>(p);
}
__device__ __forceinline__ void gload_lds16(const void* g, void* l) {
  __builtin_amdgcn_global_load_lds(
      (const __attribute__((address_space(1))) void*)g,
      (__attribute__((address_space(3))) void*)l, 16, 0, 0);
}

struct Ptrs4 { const float* p[4]; };

// ---------------- f32 -> bf16 conversions ----------------
struct CvtJob { const float* s; u16* d; int n; };
struct CvtJobs { CvtJob j[8]; };

__global__ __launch_bounds__(256) void cvt_multi(CvtJobs jobs) {
  CvtJob J = jobs.j[blockIdx.y];
  for (int i = blockIdx.x * 256 + threadIdx.x; i < J.n; i += gridDim.x * 256)
    J.d[i] = f2bf(J.s[i]);
}

// ---------------- batched transpose: in [z][C][N] f32 -> out [z][N][C] bf16 ----
struct TJob { const float* s; u16* d; int C, N, nbx, nbz, off; };
struct TJobs { TJob j[12]; };

__global__ __launch_bounds__(256) void transpose_batch(TJobs J, int nj) {
  int bid = blockIdx.x, ji = 0;
#pragma unroll
  for (int k = 1; k < 12; ++k)
    if (k < nj && bid >= J.j[k].off) ji = k;
  TJob job = J.j[ji];
  int local = bid - job.off;
  int z = local % job.nbz;
  int l2 = local / job.nbz;
  int bx = l2 % job.nbx, by = l2 / job.nbx;
  __shared__ float t[32][33];
  int tx = threadIdx.x & 31, ty = threadIdx.x >> 5;
  int n0 = bx * 32, c0 = by * 32;
  long zi = (long)z * job.C * job.N, zo = (long)z * job.N * job.C;
#pragma unroll
  for (int i = 0; i < 4; ++i)
    t[ty + 8 * i][tx] = job.s[zi + (long)(c0 + ty + 8 * i) * job.N + n0 + tx];
  __syncthreads();
#pragma unroll
  for (int i = 0; i < 4; ++i)
    job.d[zo + (long)(n0 + ty + 8 * i) * job.C + c0 + tx] = f2bf(t[tx][ty + 8 * i]);
}

// ---------------- batched GEMM: C[m][n] = sum_k A[m][k]*X[z][n][k] (+bias[m]) ----
// mode 0: o1 bf16 [z][N][M] (transposed store)
// mode 1: o1 bf16 [z][M][N]
// mode 2: o1 f32  [z][M][N], bias + optional residual res
// mode 3: KV: rows<256 -> o1 = K swizzled 16KB key-tiles [z][N/32]{[32][256] ^((key&7)<<4)}
//             rows>=256 -> o2 = V swizzled 16KB key-tiles [z][N/32]{[256][32] ^((d&7)<<4)}
struct GJob {
  const u16 *A, *X;
  const float *bias, *bias2;
  void *o1, *o2;
  const float* res;
  int M, N, K, nbx, nbz, off, mode;
};
struct GJobs { GJob j[8]; };

__global__ __launch_bounds__(256) void gemm_batch(GJobs J, int nj) {
  int bid = blockIdx.x, ji = 0;
#pragma unroll
  for (int k = 1; k < 8; ++k)
    if (k < nj && bid >= J.j[k].off) ji = k;
  GJob job = J.j[ji];
  int local = bid - job.off;
  const int z = local % job.nbz;
  int l2 = local / job.nbz;
  const int n0 = (l2 % job.nbx) * 64, m0 = (l2 / job.nbx) * 64;
  const int M = job.M, N = job.N, K = job.K;
  const u16* __restrict__ A = job.A;
  const u16* __restrict__ X = job.X;

  __shared__ __attribute__((aligned(16))) u16 As[64][40];
  __shared__ __attribute__((aligned(16))) u16 Bs[64][40];
  const int tid = threadIdx.x;
  const long Xz = (long)z * N * K;
  const int arow = tid >> 2, acol = (tid & 3) * 8;
  const int w = tid >> 6, lane = tid & 63, g = lane >> 4, ln = lane & 15;
  const int wm = (w >> 1) * 32, wn = (w & 1) * 32;
  f32x4 zero = {0.f, 0.f, 0.f, 0.f};
  f32x4 acc[2][2];
#pragma unroll
  for (int i = 0; i < 2; ++i)
#pragma unroll
    for (int j = 0; j < 2; ++j) acc[i][j] = zero;

  for (int k0 = 0; k0 < K; k0 += 32) {
    int4 av = *reinterpret_cast<const int4*>(A + (long)(m0 + arow) * K + k0 + acol);
    int4 bv = *reinterpret_cast<const int4*>(X + Xz + (long)(n0 + arow) * K + k0 + acol);
    __syncthreads();
    *reinterpret_cast<int4*>(&As[arow][acol]) = av;
    *reinterpret_cast<int4*>(&Bs[arow][acol]) = bv;
    __syncthreads();
    bf16x8 a0 = ld8(&As[wm + ln][g * 8]);
    bf16x8 a1 = ld8(&As[wm + 16 + ln][g * 8]);
    bf16x8 b0 = ld8(&Bs[wn + ln][g * 8]);
    bf16x8 b1 = ld8(&Bs[wn + 16 + ln][g * 8]);
    acc[0][0] = __builtin_amdgcn_mfma_f32_16x16x32_bf16(a0, b0, acc[0][0], 0, 0, 0);
    acc[0][1] = __builtin_amdgcn_mfma_f32_16x16x32_bf16(a0, b1, acc[0][1], 0, 0, 0);
    acc[1][0] = __builtin_amdgcn_mfma_f32_16x16x32_bf16(a1, b0, acc[1][0], 0, 0, 0);
    acc[1][1] = __builtin_amdgcn_mfma_f32_16x16x32_bf16(a1, b1, acc[1][1], 0, 0, 0);
  }

#pragma unroll
  for (int i = 0; i < 2; ++i) {
#pragma unroll
    for (int j = 0; j < 2; ++j) {
      int mr0 = m0 + wm + 16 * i + g * 4;
      int nc = n0 + wn + 16 * j + ln;
      if (job.mode == 0) {
        u64 pk = 0;
#pragma unroll
        for (int r = 0; r < 4; ++r) {
          float val = acc[i][j][r] + (job.bias ? job.bias[mr0 + r] : 0.f);
          pk |= (u64)f2bf(val) << (16 * r);
        }
        *reinterpret_cast<u64*>((u16*)job.o1 + ((long)z * N + nc) * M + mr0) = pk;
      } else if (job.mode == 1) {
#pragma unroll
        for (int r = 0; r < 4; ++r) {
          float val = acc[i][j][r] + (job.bias ? job.bias[mr0 + r] : 0.f);
          ((u16*)job.o1)[((long)z * M + mr0 + r) * N + nc] = f2bf(val);
        }
      } else if (job.mode == 2) {
#pragma unroll
        for (int r = 0; r < 4; ++r) {
          long idx = ((long)z * M + mr0 + r) * N + nc;
          float val = acc[i][j][r] + job.bias[mr0 + r];
          if (job.res) val += job.res[idx];
          ((float*)job.o1)[idx] = val;
        }
      } else {
        long tbase = (long)z * N * 256 + (long)(nc >> 5) * 8192;  // u16 elems
        if (mr0 < 256) {
          // K tile: [key 32][ch 256] bf16, byte ^= ((key&7)<<4)
          u64 pk = 0;
#pragma unroll
          for (int r = 0; r < 4; ++r)
            pk |= (u64)f2bf(acc[i][j][r] + job.bias[mr0 + r]) << (16 * r);
          int byteoff = ((nc & 31) * 512 + mr0 * 2) ^ ((nc & 7) << 4);
          *reinterpret_cast<u64*>((char*)job.o1 + tbase * 2 + byteoff) = pk;
        } else {
          // V tile: [d 256][key 32] bf16, byte ^= ((d&7)<<4)
          int d0 = mr0 - 256;
#pragma unroll
          for (int r = 0; r < 4; ++r) {
            int d = d0 + r;
            int byteoff = (d * 64 + (nc & 31) * 2) ^ ((d & 7) << 4);
            *reinterpret_cast<u16*>((char*)job.o2 + tbase * 2 + byteoff) =
                f2bf(acc[i][j][r] + job.bias2[d]);
          }
        }
      }
    }
  }
}

// ---------------- batched flash attention ------------------------------------
// Q: [z][N][256] bf16; K,V: swizzled 16KB key-tiles. O: [z][N][256] bf16.
// Block = 256 thr = 4 waves; ALL waves share one K/V stream (each wave owns 16
// queries, scans all keys). K+V double-buffered in LDS via global_load_lds.
struct AJob { const u16 *Q, *K, *V; u16* O; int N, off; };
struct AJobs { AJob j[4]; };

__global__ __launch_bounds__(256, 2) void attn_batch(AJobs J, int nj) {
  __shared__ __attribute__((aligned(16))) char stKV[2][2][16384];  // [buf][K|V]
  __shared__ __attribute__((aligned(16))) u16 Ps[4][16][40];
  int bid = blockIdx.x, ji = 0;
#pragma unroll
  for (int k = 1; k < 4; ++k)
    if (k < nj && bid >= J.j[k].off) ji = k;
  AJob job = J.j[ji];
  int local = bid - job.off;
  const int z = local & 3, bx = local >> 2;  // z fastest: pins z to XCD pairs
  const int N = job.N;
  const int tid = threadIdx.x;
  const int w = tid >> 6, lane = tid & 63;
  const int g = lane >> 4, ln = lane & 15;
  const int qrow = bx * 64 + w * 16 + ln;
  const float scale = 0.0625f;  // 1/sqrt(256)
  const int nt = N >> 5;        // 32-key tiles
  const long tb = (long)z * nt;

  // Q as B-fragments (col = query = ln)
  bf16x8 qf[8];
  {
    const u16* qp = job.Q + ((long)z * N + qrow) * 256 + g * 8;
#pragma unroll
    for (int cc = 0; cc < 8; ++cc) qf[cc] = ld8(qp + cc * 32);
  }
  f32x4 zero = {0.f, 0.f, 0.f, 0.f};
  f32x4 oacc[16];
#pragma unroll
  for (int ct = 0; ct < 16; ++ct) oacc[ct] = zero;
  float mrow = -1e30f, lrow = 0.f;

  // waves 0,1 stage the K tile; waves 2,3 stage the V tile (8KB halves each)
  const char* gsrc = (const char*)(w < 2 ? job.K : job.V);
  auto stage_tile = [&](int buf, int t) {
    const char* gp = gsrc + (tb + t) * 16384 + (w & 1) * 8192 + lane * 16;
    char* lp = &stKV[buf][w >> 1][(w & 1) * 8192];
#pragma unroll
    for (int q = 0; q < 8; ++q) gload_lds16(gp + q * 1024, lp + q * 1024);
  };

  stage_tile(0, 0);
  asm volatile("s_waitcnt vmcnt(0)" ::: "memory");
  __syncthreads();

  const int swz = (ln & 7) << 4;
  for (int t = 0; t < nt; ++t) {
    const int buf = t & 1;
    if (t + 1 < nt) stage_tile(buf ^ 1, t + 1);
    const char* Kb = &stKV[buf][0][0];
    const char* Vb = &stKV[buf][1][0];

    // S^T = K . Q^T : lane col = query ln, rows = keys g*4+r (+16 for s1)
    f32x4 s0 = zero, s1 = zero;
#pragma unroll
    for (int cc = 0; cc < 8; ++cc) {
      bf16x8 k0 = *reinterpret_cast<const bf16x8*>(Kb + ((ln * 512 + cc * 64 + g * 16) ^ swz));
      bf16x8 k1 = *reinterpret_cast<const bf16x8*>(Kb + (((16 + ln) * 512 + cc * 64 + g * 16) ^ swz));
      s0 = __builtin_amdgcn_mfma_f32_16x16x32_bf16(k0, qf[cc], s0, 0, 0, 0);
      s1 = __builtin_amdgcn_mfma_f32_16x16x32_bf16(k1, qf[cc], s1, 0, 0, 0);
    }
    float x[8];
#pragma unroll
    for (int r = 0; r < 4; ++r) { x[r] = s0[r] * scale; x[4 + r] = s1[r] * scale; }
    float lm = fmaxf(fmaxf(fmaxf(x[0], x[1]), fmaxf(x[2], x[3])),
                     fmaxf(fmaxf(x[4], x[5]), fmaxf(x[6], x[7])));
    lm = fmaxf(lm, __shfl_xor(lm, 16));
    lm = fmaxf(lm, __shfl_xor(lm, 32));
    if (!__all(lm - mrow <= 8.0f)) {  // T13 defer-max
      float nm = fmaxf(mrow, lm);
      float fac = __expf(mrow - nm);
      mrow = nm;
      lrow *= fac;
#pragma unroll
      for (int ct = 0; ct < 16; ++ct)
#pragma unroll
        for (int r = 0; r < 4; ++r) oacc[ct][r] *= fac;
    }
    float ps = 0.f;
#pragma unroll
    for (int j2 = 0; j2 < 8; ++j2) { x[j2] = __expf(x[j2] - mrow); ps += x[j2]; }
    ps += __shfl_xor(ps, 16);
    ps += __shfl_xor(ps, 32);
    lrow += ps;
    // P row -> per-wave LDS (bf16), layout [query][key 0..31]
    u64 plo = (u64)f2bf(x[0]) | ((u64)f2bf(x[1]) << 16) |
              ((u64)f2bf(x[2]) << 32) | ((u64)f2bf(x[3]) << 48);
    u64 phi = (u64)f2bf(x[4]) | ((u64)f2bf(x[5]) << 16) |
              ((u64)f2bf(x[6]) << 32) | ((u64)f2bf(x[7]) << 48);
    *reinterpret_cast<u64*>(&Ps[w][ln][g * 4]) = plo;
    *reinterpret_cast<u64*>(&Ps[w][ln][16 + g * 4]) = phi;
    asm volatile("s_waitcnt lgkmcnt(0)" ::: "memory");
    bf16x8 pa = ld8(&Ps[w][ln][g * 8]);
    // O^T += V^T . P^T
#pragma unroll
    for (int ct = 0; ct < 16; ++ct) {
      bf16x8 vv = *reinterpret_cast<const bf16x8*>(
          Vb + (((ct * 16 + ln) * 64 + g * 16) ^ swz));
      oacc[ct] = __builtin_amdgcn_mfma_f32_16x16x32_bf16(vv, pa, oacc[ct], 0, 0, 0);
    }
    asm volatile("s_waitcnt vmcnt(0)" ::: "memory");
    __syncthreads();
  }

  const float rl = 1.f / lrow;
  u16* Oz = job.O + ((long)z * N + qrow) * 256;
#pragma unroll
  for (int ct = 0; ct < 16; ++ct) {
    u64 pk = 0;
#pragma unroll
    for (int r = 0; r < 4; ++r) pk |= (u64)f2bf(oacc[ct][r] * rl) << (16 * r);
    *reinterpret_cast<u64*>(Oz + ct * 16 + g * 4) = pk;
  }
}

// ---------------- fused q bias: qeb = q_w @ vp_b + q_b ----------------
__global__ __launch_bounds__(256) void qeb_k(const float* __restrict__ qw,
                                             const float* __restrict__ qb, Ptrs4 vpb,
                                             float* __restrict__ qeb) {
  int o = threadIdx.x;
  int lvl = blockIdx.x;
  const float* vb = vpb.p[lvl];
  float acc = qb[o];
  for (int k = 0; k < 256; ++k) acc += qw[o * 256 + k] * vb[k];
  qeb[lvl * 256 + o] = acc;
}

// ---------------- pooling: t levels -> poolT [b][64 pix][1024 ch] bf16 --------
__global__ __launch_bounds__(256) void pool_k(Ptrs4 ts, u16* __restrict__ poolT) {
  int gt = blockIdx.x * 256 + threadIdx.x;
  int ch = gt & 1023;
  int pix = (gt >> 10) & 63;
  int b = gt >> 16;
  int level = ch >> 8, c = ch & 255;
  int H = 64 >> level;
  int f = H >> 3;
  int py = pix >> 3, px = pix & 7;
  const float* src = ts.p[level] + (((long)b * 256 + c) * H + py * f) * H + px * f;
  float s = 0.f;
  for (int dy = 0; dy < f; ++dy)
    for (int dx = 0; dx < f; ++dx) s += src[dy * H + dx];
  poolT[gt] = f2bf(s / (float)(f * f));
}

// ---------------- BN(train) + relu + GAP : x[4][256][64] -> xp[4][256] --------
__global__ __launch_bounds__(64) void bn_k(const float* __restrict__ x,
                                           const float* __restrict__ gw,
                                           const float* __restrict__ gb,
                                           float* __restrict__ xp) {
  int ch = blockIdx.x, t = threadIdx.x;
  float v[4], s = 0.f, sq = 0.f;
#pragma unroll
  for (int b = 0; b < 4; ++b) {
    v[b] = x[((long)b * 256 + ch) * 64 + t];
    s += v[b];
    sq += v[b] * v[b];
  }
#pragma unroll
  for (int off = 32; off; off >>= 1) {
    s += __shfl_xor(s, off);
    sq += __shfl_xor(sq, off);
  }
  float mu = s * (1.f / 256.f);
  float var = sq * (1.f / 256.f) - mu * mu;
  float rstd = rsqrtf(var + 1e-5f);
  float G = gw[ch], Bb = gb[ch];
#pragma unroll
  for (int b = 0; b < 4; ++b) {
    float y = fmaxf((v[b] - mu) * rstd * G + Bb, 0.f);
#pragma unroll
    for (int off = 32; off; off >>= 1) y += __shfl_xor(y, off);
    if (t == 0) xp[b * 256 + ch] = y * (1.f / 64.f);
  }
}

__global__ __launch_bounds__(256) void fc1_k(const float* __restrict__ xp,
                                             const float* __restrict__ w,
                                             const float* __restrict__ bias,
                                             float* __restrict__ o1) {
  int gt = blockIdx.x * 256 + threadIdx.x;  // 4096 = [b][1024]
  int b = gt >> 10, j = gt & 1023;
  float acc = bias[j];
  const float* wr = w + (long)j * 256;
  const float* xr = xp + b * 256;
  for (int k = 0; k < 256; ++k) acc += xr[k] * wr[k];
  o1[gt] = fmaxf(acc, 0.f);
}

__global__ __launch_bounds__(256) void fc2_k(const float* __restrict__ o1,
                                             const float* __restrict__ w,
                                             const float* __restrict__ bias,
                                             float* __restrict__ out) {
  int gt = blockIdx.x * 256 + threadIdx.x;  // 8192 = [b][2048]
  int b = gt >> 11, o = gt & 2047;
  float acc = bias[o];
  const float* wr = w + (long)o * 1024;
  const float* xr = o1 + b * 1024;
  for (int k = 0; k < 1024; ++k) acc += xr[k] * wr[k];
  out[gt] = acc;
}

extern "C" void kernel_launch(void* const* d_in, const int* in_sizes, int n_in,
                              void* d_out, int out_size, void* d_ws, size_t ws_size,
                              hipStream_t stream) {
  (void)in_sizes; (void)n_in; (void)out_size; (void)ws_size;
  const float *v_in[4], *t_in[4], *vp_w[4], *vp_b[4], *op_w[4], *op_b[4];
  for (int i = 0; i < 4; ++i) {
    v_in[i] = (const float*)d_in[i];
    t_in[i] = (const float*)d_in[4 + i];
    vp_w[i] = (const float*)d_in[8 + 4 * i];
    vp_b[i] = (const float*)d_in[9 + 4 * i];
    op_w[i] = (const float*)d_in[10 + 4 * i];
    op_b[i] = (const float*)d_in[11 + 4 * i];
  }
  const float* q_w = (const float*)d_in[24];
  const float* q_b = (const float*)d_in[25];
  const float* k_w = (const float*)d_in[26];
  const float* k_b = (const float*)d_in[27];
  const float* v_w = (const float*)d_in[28];
  const float* v_b = (const float*)d_in[29];
  const float* sg_w = (const float*)d_in[30];
  const float* sg_b = (const float*)d_in[31];
  const float* bn_g = (const float*)d_in[32];
  const float* bn_b = (const float*)d_in[33];
  const float* fc1_w = (const float*)d_in[34];
  const float* fc1_b = (const float*)d_in[35];
  const float* fc2_w = (const float*)d_in[36];
  const float* fc2_b = (const float*)d_in[37];
  float* out = (float*)d_out;

  const int cin[4] = {64, 128, 256, 512};
  const int NN[4] = {4096, 1024, 256, 64};
  const long NOFF[4] = {0, 4194304, 5242880, 5505024};  // 4*N*256 cumsum
  const long VOFF[4] = {0, 1048576, 1572864, 1835008};  // 4*N*cin cumsum

  char* ws = (char*)d_ws;
  size_t off = 0;
  auto alloc = [&](size_t bytes) {
    void* p = ws + off;
    off += (bytes + 255) & ~(size_t)255;
    return p;
  };
  u16* w_q = (u16*)alloc(65536 * 2);
  u16* w_kv = (u16*)alloc(131072 * 2);
  u16* w_op[4];
  for (int i = 0; i < 4; ++i) w_op[i] = (u16*)alloc((size_t)cin[i] * 256 * 2);
  u16* w_sg = (u16*)alloc(262144 * 2);
  u16* vpwT[4];
  for (int i = 0; i < 4; ++i) vpwT[i] = (u16*)alloc((size_t)cin[i] * 256 * 2);
  u16* qe[4];
  for (int i = 0; i < 4; ++i) qe[i] = (u16*)alloc((size_t)256 * cin[i] * 2);
  float* qeb = (float*)alloc(1024 * 4);
  u16* vT = (u16*)alloc((size_t)1966080 * 2);
  u16* tT = (u16*)alloc((size_t)5570560 * 2);
  u16* QT = (u16*)alloc((size_t)5570560 * 2);
  u16* Kt = (u16*)alloc((size_t)5570560 * 2);
  u16* Vt = (u16*)alloc((size_t)5570560 * 2);
  u16* Ob = (u16*)alloc((size_t)5570560 * 2);
  u16* poolT = (u16*)alloc((size_t)262144 * 2);
  float* xbuf = (float*)alloc((size_t)65536 * 4);
  float* xp = (float*)alloc(1024 * 4);
  float* fc1o = (float*)alloc(4096 * 4);

  // 1) weights -> bf16
  CvtJobs jobs;
  jobs.j[0] = {q_w, w_q, 65536};
  jobs.j[1] = {k_w, w_kv, 65536};
  jobs.j[2] = {v_w, w_kv + 65536, 65536};
  jobs.j[3] = {op_w[0], w_op[0], cin[0] * 256};
  jobs.j[4] = {op_w[1], w_op[1], cin[1] * 256};
  jobs.j[5] = {op_w[2], w_op[2], cin[2] * 256};
  jobs.j[6] = {op_w[3], w_op[3], cin[3] * 256};
  jobs.j[7] = {sg_w, w_sg, 262144};
  cvt_multi<<<dim3(32, 8), 256, 0, stream>>>(jobs);

  // 2) batched transposes: vp_w (4), v (4), t (4)
  {
    TJobs T;
    int boff = 0, nj = 0;
    for (int i = 0; i < 4; ++i) {
      int nbx = cin[i] / 32;
      T.j[nj] = {vp_w[i], vpwT[i], 256, cin[i], nbx, 1, boff};
      boff += nbx * 8;
      ++nj;
    }
    for (int i = 0; i < 4; ++i) {
      int nbx = NN[i] / 32, nby = cin[i] / 32;
      T.j[nj] = {v_in[i], vT + VOFF[i], cin[i], NN[i], nbx, 4, boff};
      boff += nbx * nby * 4;
      ++nj;
    }
    for (int i = 0; i < 4; ++i) {
      int nbx = NN[i] / 32;
      T.j[nj] = {t_in[i], tT + NOFF[i], 256, NN[i], nbx, 4, boff};
      boff += nbx * 8 * 4;
      ++nj;
    }
    transpose_batch<<<boff, 256, 0, stream>>>(T, nj);
  }

  // 3) qe = q_w @ vp_w (4 jobs, mode 1)
  {
    GJobs G;
    int boff = 0;
    for (int i = 0; i < 4; ++i) {
      int nbx = cin[i] / 64;
      G.j[i] = {w_q, vpwT[i], nullptr, nullptr, qe[i], nullptr, nullptr,
                256, cin[i], 256, nbx, 1, boff, 1};
      boff += nbx * 4;
    }
    gemm_batch<<<boff, 256, 0, stream>>>(G, 4);
  }
  Ptrs4 vpbp;
  for (int i = 0; i < 4; ++i) vpbp.p[i] = vp_b[i];
  qeb_k<<<4, 256, 0, stream>>>(q_w, q_b, vpbp, qeb);

  // 4) Q-proj (mode 0) + KV-proj (mode 3) in ONE launch (8 jobs)
  {
    GJobs G;
    int boff = 0, nj = 0;
    for (int i = 0; i < 4; ++i) {
      int nbx = NN[i] / 64;
      G.j[nj] = {qe[i], vT + VOFF[i], qeb + 256 * i, nullptr, QT + NOFF[i], nullptr,
                 nullptr, 256, NN[i], cin[i], nbx, 4, boff, 0};
      boff += nbx * 4 * 4;
      ++nj;
    }
    for (int i = 0; i < 4; ++i) {
      int nbx = NN[i] / 64;
      G.j[nj] = {w_kv, tT + NOFF[i], k_b, v_b, Kt + NOFF[i], Vt + NOFF[i], nullptr,
                 512, NN[i], 256, nbx, 4, boff, 3};
      boff += nbx * 8 * 4;
      ++nj;
    }
    gemm_batch<<<boff, 256, 0, stream>>>(G, 8);
  }

  // 5) attention (4 jobs, one launch)
  {
    AJobs A;
    int boff = 0;
    for (int i = 0; i < 4; ++i) {
      A.j[i] = {QT + NOFF[i], Kt + NOFF[i], Vt + NOFF[i], Ob + NOFF[i], NN[i], boff};
      boff += (NN[i] / 64) * 4;
    }
    attn_batch<<<boff, 256, 0, stream>>>(A, 4);
  }

  // 6) pooling for semantic branch
  Ptrs4 tp;
  for (int i = 0; i < 4; ++i) tp.p[i] = t_in[i];
  pool_k<<<1024, 256, 0, stream>>>(tp, poolT);

  // 7) op-proj + residual (4 jobs) and sg-gemm (1 job), mode 2
  const long enh_off[4] = {8192, 8192 + 1048576, 8192 + 1048576 + 524288,
                           8192 + 1048576 + 524288 + 262144};
  {
    GJobs G;
    int boff = 0;
    for (int i = 0; i < 4; ++i) {
      int nbx = NN[i] / 64, nby = cin[i] / 64;
      G.j[i] = {w_op[i], Ob + NOFF[i], op_b[i], nullptr, out + enh_off[i], nullptr,
                v_in[i], cin[i], NN[i], 256, nbx, 4, boff, 2};
      boff += nbx * nby * 4;
    }
    G.j[4] = {w_sg, poolT, sg_b, nullptr, xbuf, nullptr, nullptr,
              256, 64, 1024, 1, 4, boff, 2};
    boff += 1 * 4 * 4;
    gemm_batch<<<boff, 256, 0, stream>>>(G, 5);
  }

  // 8) semantic tail
  bn_k<<<256, 64, 0, stream>>>(xbuf, bn_g, bn_b, xp);
  fc1_k<<<16, 256, 0, stream>>>(xp, fc1_w, fc1_b, fc1o);
  fc2_k<<<32, 256, 0, stream>>>(fc1o, fc2_w, fc2_b, out);
}